// Round 3
// baseline (596.433 us; speedup 1.0000x reference)
//
#include <hip/hip_runtime.h>

constexpr int NL    = 48;
constexpr int SEQ   = 1024;
constexpr int BATCH = 512;

// One step of the linear-domain forward recurrence, LDS-broadcast version.
// v-vector lives in vb4[] (48 floats). Each lane reads the whole vector via
// 12 x ds_read_b128 (same address across lanes -> broadcast, no conflicts,
// no SGPR-write hazards), does 48 fma paired as float2 (pk_fma-friendly),
// then writes its new v element back. RN_: fold renorm max out of the same
// broadcast data (wave-uniform result computed redundantly per-lane; no
// serial shfl chain on the critical path).
#define CRF_STEP(T_, SLOT_, RN_) do {                                         \
    float ee_ = __expf(embuf[SLOT_]);                                         \
    int   mt_ = mbuf[SLOT_];                                                  \
    int   tn_ = (T_) + 8; if (tn_ > SEQ - 1) tn_ = SEQ - 1;                   \
    embuf[SLOT_] = em[tn_ * NL + jc];                                         \
    mbuf[SLOT_]  = mk[tn_];                                                   \
    float2 c0_={0.f,0.f}, c1_={0.f,0.f}, c2_={0.f,0.f}, c3_={0.f,0.f};        \
    float2 mx_={0.f,0.f};                                                     \
    _Pragma("unroll")                                                         \
    for (int r_ = 0; r_ < 12; ++r_) {                                         \
        float4 q_  = vb4[r_];                                                 \
        float2 eA_ = Ec2[2*r_], eB_ = Ec2[2*r_+1];                            \
        if (RN_) {                                                            \
            mx_.x = fmaxf(mx_.x, fmaxf(q_.x, q_.z));                          \
            mx_.y = fmaxf(mx_.y, fmaxf(q_.y, q_.w));                          \
        }                                                                     \
        if (r_ & 1) {                                                         \
            c2_.x = fmaf(q_.x, eA_.x, c2_.x); c2_.y = fmaf(q_.y, eA_.y, c2_.y);\
            c3_.x = fmaf(q_.z, eB_.x, c3_.x); c3_.y = fmaf(q_.w, eB_.y, c3_.y);\
        } else {                                                              \
            c0_.x = fmaf(q_.x, eA_.x, c0_.x); c0_.y = fmaf(q_.y, eA_.y, c0_.y);\
            c1_.x = fmaf(q_.z, eB_.x, c1_.x); c1_.y = fmaf(q_.w, eB_.y, c1_.y);\
        }                                                                     \
    }                                                                         \
    float2 d0_ = {c0_.x + c2_.x, c0_.y + c2_.y};                              \
    float2 d1_ = {c1_.x + c3_.x, c1_.y + c3_.y};                              \
    float acc_ = (d0_.x + d0_.y) + (d1_.x + d1_.y);                           \
    float nv_  = mt_ ? acc_ * ee_ : v;                                        \
    if (RN_) {                                                                \
        float m_ = fmaxf(fmaxf(mx_.x, mx_.y), 1e-30f);                        \
        nv_ *= __builtin_amdgcn_rcpf(m_);                                     \
        S += __logf(m_);                                                      \
    }                                                                         \
    v = nv_;                                                                  \
    vb[jc] = v;                                                               \
} while (0)

// Block = 128: wave 0 = forward recurrence, wave 1 = gold score (hides under
// forward's 1023-step latency chain, shares L1/L2).
__global__ __launch_bounds__(128, 1) void crf_fused(
    const float* __restrict__ emissions, const int* __restrict__ labels,
    const int* __restrict__ mask, const float* __restrict__ trans,
    const float* __restrict__ startt, const float* __restrict__ endt,
    float* __restrict__ gold_out, float* __restrict__ fwd_out)
{
    __shared__ float4 vb4[12];                 // 48 floats: the v-vector
    const int b   = blockIdx.x;
    const int tid = threadIdx.x;
    const float* em = emissions + (size_t)b * SEQ * NL;
    const int*   mk = mask + b * SEQ;

    if (tid < 64) {
        // ---------------- wave 0: forward algorithm ----------------
        const int  j   = tid;
        const bool act = (j < NL);
        const int  jc  = act ? j : NL - 1;     // lanes 48..63 mirror lane 47
        float* vb = (float*)vb4;

        // E column jc as float2 pairs: Ec2[p] = (exp T[2p][jc], exp T[2p+1][jc]).
        float2 Ec2[24];
        #pragma unroll
        for (int p = 0; p < 24; ++p) {
            Ec2[p].x = __expf(trans[(2*p)     * NL + jc]);
            Ec2[p].y = __expf(trans[(2*p + 1) * NL + jc]);
        }

        // init: score0 = start + emit[0]; normalize by wave max.
        // Lanes 48..63 compute exactly lane 47's values -> their duplicate
        // LDS writes to vb[47] carry identical bits (benign).
        float s0 = startt[jc] + em[jc];
        float m0 = s0;
        #pragma unroll
        for (int o = 32; o; o >>= 1) m0 = fmaxf(m0, __shfl_xor(m0, o));
        float v = __expf(s0 - m0);
        float S = m0;
        vb[jc] = v;

        // 8-deep prefetch ring for emissions + mask.
        float embuf[8]; int mbuf[8];
        #pragma unroll
        for (int t = 1; t <= 8; ++t) { embuf[t & 7] = em[t * NL + jc]; mbuf[t & 7] = mk[t]; }

        // peeled steps 1..7, renorm at t=4.
        CRF_STEP(1, 1, 0); CRF_STEP(2, 2, 0); CRF_STEP(3, 3, 0);
        CRF_STEP(4, 4, 1);
        CRF_STEP(5, 5, 0); CRF_STEP(6, 6, 0); CRF_STEP(7, 7, 0);

        // aligned chunks of 8: tb = 8,16,...,1016 covers t = 8..1023.
        // renorm every 4 steps (growth bound ~2^82 between renorms, safe in fp32).
        for (int tb = 8; tb <= SEQ - 8; tb += 8) {
            CRF_STEP(tb + 0, 0, 1);
            CRF_STEP(tb + 1, 1, 0); CRF_STEP(tb + 2, 2, 0); CRF_STEP(tb + 3, 3, 0);
            CRF_STEP(tb + 4, 4, 1);
            CRF_STEP(tb + 5, 5, 0); CRF_STEP(tb + 6, 6, 0); CRF_STEP(tb + 7, 7, 0);
        }

        // fwd = S + log(sum_j v[j] * exp(end[j])) over active lanes only.
        float w = act ? v * __expf(endt[jc]) : 0.0f;
        #pragma unroll
        for (int o = 32; o; o >>= 1) w += __shfl_xor(w, o);
        if (j == 0) fwd_out[b] = S + __logf(w);
    } else {
        // ---------------- wave 1: gold score ----------------
        const int l = tid - 64;
        const int* lb = labels + b * SEQ;

        float part = 0.0f; int mcnt = 0;
        for (int t = l; t < SEQ; t += 64) {
            int lt = lb[t];
            int mt = mk[t];
            mcnt += mt;
            if (t == 0) {
                part += startt[lt] + em[lt];
            } else {
                float e  = em[t * NL + lt];
                float tr = trans[lt * NL + lb[t - 1]];   // gold uses T[cur][prev]
                if (mt) part += e + tr;
            }
        }
        #pragma unroll
        for (int o = 32; o; o >>= 1) {
            part += __shfl_xor(part, o);
            mcnt += __shfl_xor(mcnt, o);
        }
        if (l == 0) {
            int len = mcnt - 1;
            gold_out[b] = part + endt[lb[len]];
        }
    }
}

__global__ __launch_bounds__(64) void crf_reduce(
    const float* __restrict__ gold, const float* __restrict__ fwd,
    float* __restrict__ out)
{
    const int l = threadIdx.x;
    float s = 0.0f;
    for (int bIdx = l; bIdx < BATCH; bIdx += 64) s += fwd[bIdx] - gold[bIdx];
    #pragma unroll
    for (int o = 32; o; o >>= 1) s += __shfl_xor(s, o);
    if (l == 0) out[0] = s * (1.0f / (float)BATCH);
}

extern "C" void kernel_launch(void* const* d_in, const int* in_sizes, int n_in,
                              void* d_out, int out_size, void* d_ws, size_t ws_size,
                              hipStream_t stream) {
    const float* emissions = (const float*)d_in[0];
    const int*   labels    = (const int*)d_in[1];
    const int*   mask      = (const int*)d_in[2];
    const float* trans     = (const float*)d_in[3];
    const float* startt    = (const float*)d_in[4];
    const float* endt      = (const float*)d_in[5];
    float*       out       = (float*)d_out;
    float*       wsf       = (float*)d_ws;   // [0..512) gold, [512..1024) fwd

    crf_fused<<<BATCH, 128, 0, stream>>>(emissions, labels, mask, trans, startt, endt,
                                         wsf, wsf + BATCH);
    crf_reduce<<<1, 64, 0, stream>>>(wsf, wsf + BATCH, out);
}

// Round 4
// 356.180 us; speedup vs baseline: 1.6745x; 1.6745x over previous
//
#include <hip/hip_runtime.h>

constexpr int NL    = 48;
constexpr int SEQ   = 1024;
constexpr int BATCH = 512;

__device__ __forceinline__ float lane_bcast(float v, int lane) {
    return __int_as_float(__builtin_amdgcn_readlane(__float_as_int(v), lane));
}

// One step of the linear-domain forward recurrence (readlane-broadcast).
// Phase 1: broadcast all 48 v-values into wave-uniform (SGPR) temps sv_[].
// Phase 2: 48 FMAs against per-lane column Ec[] on 4 accumulator chains.
// RN_: renorm using a scalar-pipe (s_max_u32) max over the uniform sv_[]
// values (positive floats order like unsigned ints) — renormalizes the
// PRE-step v; scale is folded into this step's output on both mask paths,
// so it is exactly equivalent.
#define CRF_STEP(T_, SLOT_, RN_) do {                                         \
    float ee_ = __expf(embuf[SLOT_]);                                         \
    int   mt_ = mbuf[SLOT_];                                                  \
    int   tn_ = (T_) + 8; if (tn_ > SEQ - 1) tn_ = SEQ - 1;                   \
    embuf[SLOT_] = em[tn_ * NL + jc];                                         \
    mbuf[SLOT_]  = mk[tn_];                                                   \
    float sv_[NL];                                                            \
    _Pragma("unroll")                                                         \
    for (int i_ = 0; i_ < NL; ++i_) sv_[i_] = lane_bcast(v, i_);              \
    float rm_ = 1.0f;                                                         \
    if (RN_) {                                                                \
        unsigned um_ = __float_as_uint(sv_[0]);                               \
        _Pragma("unroll")                                                     \
        for (int i_ = 1; i_ < NL; ++i_) {                                     \
            unsigned u2_ = __float_as_uint(sv_[i_]);                          \
            um_ = (um_ > u2_) ? um_ : u2_;                                    \
        }                                                                     \
        float m_ = __uint_as_float(um_);                                      \
        rm_ = __builtin_amdgcn_rcpf(m_);                                      \
        S += __logf(m_);                                                      \
    }                                                                         \
    float a0_ = 0.f, a1_ = 0.f, a2_ = 0.f, a3_ = 0.f;                         \
    _Pragma("unroll")                                                         \
    for (int i_ = 0; i_ < NL; i_ += 4) {                                      \
        a0_ = fmaf(sv_[i_ + 0], Ec[i_ + 0], a0_);                             \
        a1_ = fmaf(sv_[i_ + 1], Ec[i_ + 1], a1_);                             \
        a2_ = fmaf(sv_[i_ + 2], Ec[i_ + 2], a2_);                             \
        a3_ = fmaf(sv_[i_ + 3], Ec[i_ + 3], a3_);                             \
    }                                                                         \
    float acc_ = (a0_ + a1_) + (a2_ + a3_);                                   \
    v = (mt_ ? acc_ * ee_ : v) * rm_;                                         \
} while (0)

// Block = 128: wave 0 = forward recurrence, wave 1 = gold score.
// amdgpu_waves_per_eu(1,1): target exactly 1 wave/EU so the register
// allocator gets the full ~512-VGPR budget and keeps Ec[48] in
// architectural VGPRs (rounds 1-3 capped at 60-72 VGPRs -> AGPR shuffling
// in the inner loop was the dominant per-step cost).
__global__ __launch_bounds__(128)
__attribute__((amdgpu_waves_per_eu(1, 1)))
void crf_fused(
    const float* __restrict__ emissions, const int* __restrict__ labels,
    const int* __restrict__ mask, const float* __restrict__ trans,
    const float* __restrict__ startt, const float* __restrict__ endt,
    float* __restrict__ gold_out, float* __restrict__ fwd_out)
{
    const int b   = blockIdx.x;
    const int tid = threadIdx.x;
    const float* em = emissions + (size_t)b * SEQ * NL;
    const int*   mk = mask + b * SEQ;

    if (tid < 64) {
        // ---------------- wave 0: forward algorithm ----------------
        const int  j   = tid;                  // lanes 48..63 idle mirrors
        const bool act = (j < NL);
        const int  jc  = act ? j : NL - 1;

        // E column jc in registers: Ec[i] = exp(T[i][jc]).
        float Ec[NL];
        #pragma unroll
        for (int i = 0; i < NL; ++i) Ec[i] = __expf(trans[i * NL + jc]);

        // init: score0 = start + emit[0]; normalize by wave max.
        float s0 = act ? (startt[jc] + em[jc]) : -3.0e38f;
        float m0 = s0;
        #pragma unroll
        for (int o = 32; o; o >>= 1) m0 = fmaxf(m0, __shfl_xor(m0, o));
        float v = act ? __expf(s0 - m0) : 0.0f;
        float S = m0;

        // 8-deep prefetch ring for emissions + mask.
        float embuf[8]; int mbuf[8];
        #pragma unroll
        for (int t = 1; t <= 8; ++t) { embuf[t & 7] = em[t * NL + jc]; mbuf[t & 7] = mk[t]; }

        // peeled steps 1..7; renorm at step 5 (v from step 4).
        CRF_STEP(1, 1, 0); CRF_STEP(2, 2, 0); CRF_STEP(3, 3, 0); CRF_STEP(4, 4, 0);
        CRF_STEP(5, 5, 1); CRF_STEP(6, 6, 0); CRF_STEP(7, 7, 0);

        // aligned chunks of 8: tb = 8,16,...,1016 covers t = 8..1023.
        // renorm at tb+0 and tb+4 -> every <=4 steps (fp32-safe growth).
        for (int tb = 8; tb <= SEQ - 8; tb += 8) {
            CRF_STEP(tb + 0, 0, 1);
            CRF_STEP(tb + 1, 1, 0); CRF_STEP(tb + 2, 2, 0); CRF_STEP(tb + 3, 3, 0);
            CRF_STEP(tb + 4, 4, 1);
            CRF_STEP(tb + 5, 5, 0); CRF_STEP(tb + 6, 6, 0); CRF_STEP(tb + 7, 7, 0);
        }

        // fwd = S + log(sum_j v[j] * exp(end[j])) over active lanes.
        float w = act ? v * __expf(endt[jc]) : 0.0f;
        #pragma unroll
        for (int o = 32; o; o >>= 1) w += __shfl_xor(w, o);
        if (j == 0) fwd_out[b] = S + __logf(w);
    } else {
        // ---------------- wave 1: gold score ----------------
        const int l = tid - 64;
        const int* lb = labels + b * SEQ;

        float part = 0.0f; int mcnt = 0;
        for (int t = l; t < SEQ; t += 64) {
            int lt = lb[t];
            int mt = mk[t];
            mcnt += mt;
            if (t == 0) {
                part += startt[lt] + em[lt];
            } else {
                float e  = em[t * NL + lt];
                float tr = trans[lt * NL + lb[t - 1]];   // gold uses T[cur][prev]
                if (mt) part += e + tr;
            }
        }
        #pragma unroll
        for (int o = 32; o; o >>= 1) {
            part += __shfl_xor(part, o);
            mcnt += __shfl_xor(mcnt, o);
        }
        if (l == 0) {
            int len = mcnt - 1;
            gold_out[b] = part + endt[lb[len]];
        }
    }
}

__global__ __launch_bounds__(64) void crf_reduce(
    const float* __restrict__ gold, const float* __restrict__ fwd,
    float* __restrict__ out)
{
    const int l = threadIdx.x;
    float s = 0.0f;
    for (int bIdx = l; bIdx < BATCH; bIdx += 64) s += fwd[bIdx] - gold[bIdx];
    #pragma unroll
    for (int o = 32; o; o >>= 1) s += __shfl_xor(s, o);
    if (l == 0) out[0] = s * (1.0f / (float)BATCH);
}

extern "C" void kernel_launch(void* const* d_in, const int* in_sizes, int n_in,
                              void* d_out, int out_size, void* d_ws, size_t ws_size,
                              hipStream_t stream) {
    const float* emissions = (const float*)d_in[0];
    const int*   labels    = (const int*)d_in[1];
    const int*   mask      = (const int*)d_in[2];
    const float* trans     = (const float*)d_in[3];
    const float* startt    = (const float*)d_in[4];
    const float* endt      = (const float*)d_in[5];
    float*       out       = (float*)d_out;
    float*       wsf       = (float*)d_ws;   // [0..512) gold, [512..1024) fwd

    crf_fused<<<BATCH, 128, 0, stream>>>(emissions, labels, mask, trans, startt, endt,
                                         wsf, wsf + BATCH);
    crf_reduce<<<1, 64, 0, stream>>>(wsf, wsf + BATCH, out);
}